// Round 2
// baseline (1661.845 us; speedup 1.0000x reference)
//
#include <hip/hip_runtime.h>
#include <cstdint>
#include <cmath>

#define B_ 2
#define T_ 2048
#define C_ 2048
#define H_ 32
#define BT_ (B_ * T_)
#define BTC_ ((size_t)B_ * T_ * C_)
#define L_ 128
#define NC_ 16

typedef __attribute__((ext_vector_type(4))) float f32x4;
typedef __attribute__((ext_vector_type(2))) float f32x2;
typedef __attribute__((ext_vector_type(8))) short bf16x8;
typedef __attribute__((ext_vector_type(4))) unsigned short us4;
typedef __attribute__((ext_vector_type(4))) int i32x4;

__device__ __forceinline__ unsigned short f2bf(float f) {
  union { float f; unsigned int u; } c; c.f = f;
  unsigned int u = c.u;
  return (unsigned short)((u + 0x7FFFu + ((u >> 16) & 1u)) >> 16);
}
__device__ __forceinline__ float bf2f(unsigned short h) {
  union { unsigned int u; float f; } c; c.u = ((unsigned int)h) << 16;
  return c.f;
}
__device__ __forceinline__ float rlane(float v, int lane) {
  return __int_as_float(__builtin_amdgcn_readlane(__float_as_int(v), lane));
}
__device__ __forceinline__ void split4(f32x4 v, us4& h, us4& l) {
  h.x = f2bf(v.x); l.x = f2bf(v.x - bf2f(h.x));
  h.y = f2bf(v.y); l.y = f2bf(v.y - bf2f(h.y));
  h.z = f2bf(v.z); l.z = f2bf(v.z - bf2f(h.z));
  h.w = f2bf(v.w); l.w = f2bf(v.w - bf2f(h.w));
}
// async global->LDS, 16 B per lane; LDS dest = wave-uniform base + lane*16
__device__ __forceinline__ void g2l(const void* g, void* l) {
  __builtin_amdgcn_global_load_lds((const __attribute__((address_space(1))) void*)g,
                                   (__attribute__((address_space(3))) void*)l, 16, 0, 0);
}

// ---------------- token shift + mixes: r/k/v as bf16 hi+lo pairs, w/a/g bf16 ----------------
__global__ __launch_bounds__(256) void k_mix(
    const float* __restrict__ x, const float* __restrict__ shift,
    const float* __restrict__ m_r, const float* __restrict__ m_w,
    const float* __restrict__ m_k, const float* __restrict__ m_v,
    const float* __restrict__ m_a, const float* __restrict__ m_g,
    unsigned short* __restrict__ r_h, unsigned short* __restrict__ r_l,
    unsigned short* __restrict__ k_h, unsigned short* __restrict__ k_l,
    unsigned short* __restrict__ v_h, unsigned short* __restrict__ v_l,
    unsigned short* __restrict__ o_w, unsigned short* __restrict__ o_a,
    unsigned short* __restrict__ o_g,
    float* __restrict__ xlast) {
  size_t i4 = ((size_t)blockIdx.x * 256 + threadIdx.x) * 4;
  int c = (int)(i4 % C_);
  size_t bt = i4 / C_;
  int t = (int)(bt % T_);
  int b = (int)(bt / T_);
  f32x4 xv = *(const f32x4*)(x + i4);
  f32x4 pv = (t == 0) ? *(const f32x4*)(shift + (size_t)b * C_ + c)
                      : *(const f32x4*)(x + i4 - C_);
  f32x4 dx = pv - xv;
#define MIXHL(mp, oh, ol) { f32x4 mm = *(const f32x4*)(mp + c); f32x4 rr = xv + dx * mm; \
    us4 hh, ll; split4(rr, hh, ll); *(us4*)(oh + i4) = hh; *(us4*)(ol + i4) = ll; }
#define MIXH(mp, oh) { f32x4 mm = *(const f32x4*)(mp + c); f32x4 rr = xv + dx * mm; \
    us4 pk; pk.x = f2bf(rr.x); pk.y = f2bf(rr.y); pk.z = f2bf(rr.z); pk.w = f2bf(rr.w); \
    *(us4*)(oh + i4) = pk; }
  MIXHL(m_r, r_h, r_l) MIXHL(m_k, k_h, k_l) MIXHL(m_v, v_h, v_l)
  MIXH(m_w, o_w) MIXH(m_a, o_a) MIXH(m_g, o_g)
#undef MIXHL
#undef MIXH
  if (t == T_ - 1) *(f32x4*)(xlast + (size_t)b * C_ + c) = xv;
}

// ---------------- f32 [R][Cc] -> bf16 [Cc][R] transpose ----------------
__global__ __launch_bounds__(256) void k_tr(const float* __restrict__ in,
                                            unsigned short* __restrict__ out,
                                            int R, int Cc) {
  __shared__ float tile[32][33];
  int c0 = blockIdx.x * 32, r0 = blockIdx.y * 32;
  int tid = threadIdx.x;
  int rr = tid >> 3, c4 = (tid & 7) * 4;
  f32x4 v = *(const f32x4*)(in + (size_t)(r0 + rr) * Cc + c0 + c4);
  tile[rr][c4] = v.x; tile[rr][c4 + 1] = v.y; tile[rr][c4 + 2] = v.z; tile[rr][c4 + 3] = v.w;
  __syncthreads();
  int cc = tid >> 3, r4 = (tid & 7) * 4;
  us4 o;
  o.x = f2bf(tile[r4][cc]); o.y = f2bf(tile[r4 + 1][cc]);
  o.z = f2bf(tile[r4 + 2][cc]); o.w = f2bf(tile[r4 + 3][cc]);
  *(us4*)(out + (size_t)(c0 + cc) * R + r0 + r4) = o;
}

// ---------------- f32 [R][Cc] -> bf16 hi+lo [Cc][R] split transpose ----------------
__global__ __launch_bounds__(256) void k_trs(const float* __restrict__ in,
                                             unsigned short* __restrict__ oh,
                                             unsigned short* __restrict__ ol,
                                             int R, int Cc) {
  __shared__ float tile[32][33];
  int c0 = blockIdx.x * 32, r0 = blockIdx.y * 32;
  int tid = threadIdx.x;
  int rr = tid >> 3, c4 = (tid & 7) * 4;
  f32x4 v = *(const f32x4*)(in + (size_t)(r0 + rr) * Cc + c0 + c4);
  tile[rr][c4] = v.x; tile[rr][c4 + 1] = v.y; tile[rr][c4 + 2] = v.z; tile[rr][c4 + 3] = v.w;
  __syncthreads();
  int cc = tid >> 3, r4 = (tid & 7) * 4;
  f32x4 w = { tile[r4][cc], tile[r4 + 1][cc], tile[r4 + 2][cc], tile[r4 + 3][cc] };
  us4 h, l; split4(w, h, l);
  size_t o = (size_t)(c0 + cc) * R + r0 + r4;
  *(us4*)(oh + o) = h; *(us4*)(ol + o) = l;
}

// ---------------- bf16 GEMM: C[M,N] = X[M,K] @ Wt[N,K]^T (global_load_lds staging) ----------------
// XCD-aware bijective block swizzle (T1): all launch grids have nwg % 8 == 0.
__global__ __launch_bounds__(256) void k_gemm(
    const unsigned short* __restrict__ X, const unsigned short* __restrict__ Wt,
    void* __restrict__ out, int M, int N, int K, int mode) {
  __shared__ alignas(16) unsigned short As[128 * 32];
  __shared__ alignas(16) unsigned short Bs[128 * 32];
  const int tid = threadIdx.x;
  const int lane = tid & 63, wave = tid >> 6;
  const int wr = wave >> 1, wc = wave & 1;
  const int lm = lane & 15, lq = lane >> 4;
  const int gx = gridDim.x;
  const int nwg = gx * gridDim.y;
  const int bid = blockIdx.y * gx + blockIdx.x;
  const int sz = (bid & 7) * (nwg >> 3) + (bid >> 3);
  const int m0 = (sz / gx) * 128, n0 = (sz % gx) * 128;
  const int srow = (lane >> 2);
  const int kcol = (lane & 3) * 8;
  f32x4 acc[4][4];
#pragma unroll
  for (int i = 0; i < 4; ++i)
#pragma unroll
    for (int j = 0; j < 4; ++j) acc[i][j] = (f32x4){0.f, 0.f, 0.f, 0.f};

  for (int k0 = 0; k0 < K; k0 += 32) {
#pragma unroll
    for (int p = 0; p < 2; ++p) {
      int row = wave * 32 + p * 16 + srow;
      g2l(X + (size_t)(m0 + row) * K + k0 + kcol, As + (wave * 2 + p) * 512);
      int n = n0 + row; if (n > N - 1) n = N - 1;
      g2l(Wt + (size_t)n * K + k0 + kcol, Bs + (wave * 2 + p) * 512);
    }
    __syncthreads();
    bf16x8 af[4], bfr[4];
#pragma unroll
    for (int i = 0; i < 4; ++i)
      af[i] = *(const bf16x8*)(As + (size_t)(wr * 64 + i * 16 + lm) * 32 + lq * 8);
#pragma unroll
    for (int j = 0; j < 4; ++j)
      bfr[j] = *(const bf16x8*)(Bs + (size_t)(wc * 64 + j * 16 + lm) * 32 + lq * 8);
#pragma unroll
    for (int i = 0; i < 4; ++i)
#pragma unroll
      for (int j = 0; j < 4; ++j)
        acc[i][j] = __builtin_amdgcn_mfma_f32_16x16x32_bf16(af[i], bfr[j], acc[i][j], 0, 0, 0);
    __syncthreads();
  }
#pragma unroll
  for (int i = 0; i < 4; ++i)
#pragma unroll
    for (int j = 0; j < 4; ++j) {
      int n = n0 + wc * 64 + j * 16 + lm;
      if (n >= N) continue;
      int mb = m0 + wr * 64 + i * 16 + lq * 4;
#pragma unroll
      for (int r = 0; r < 4; ++r) {
        float val = acc[i][j][r];
        size_t off = (size_t)(mb + r) * N + n;
        if (mode == 0) {
          ((float*)out)[off] = val;
        } else {
          if (mode == 2) val = tanhf(val);
          else if (mode == 3) val = 1.0f / (1.0f + __expf(-val));
          ((unsigned short*)out)[off] = f2bf(val);
        }
      }
    }
}

// ---------------- split (hi+lo) bf16 GEMM: hh + lh + hl (ll dropped, ~2^-17 rel) ----------------
__global__ __launch_bounds__(256) void k_gemm2(
    const unsigned short* __restrict__ Xh, const unsigned short* __restrict__ Xl, int xlo,
    const unsigned short* __restrict__ Wh, const unsigned short* __restrict__ Wl, int wlo,
    void* __restrict__ out, int M, int N, int K, int mode) {
  __shared__ alignas(16) unsigned short Ah[128 * 32];
  __shared__ alignas(16) unsigned short Al[128 * 32];
  __shared__ alignas(16) unsigned short Bh[128 * 32];
  __shared__ alignas(16) unsigned short Bl[128 * 32];
  const int tid = threadIdx.x;
  const int lane = tid & 63, wave = tid >> 6;
  const int wr = wave >> 1, wc = wave & 1;
  const int lm = lane & 15, lq = lane >> 4;
  const int gx = gridDim.x;
  const int nwg = gx * gridDim.y;
  const int bid = blockIdx.y * gx + blockIdx.x;
  const int sz = (bid & 7) * (nwg >> 3) + (bid >> 3);
  const int m0 = (sz / gx) * 128, n0 = (sz % gx) * 128;
  const int srow = (lane >> 2);
  const int kcol = (lane & 3) * 8;
  f32x4 acc[4][4];
#pragma unroll
  for (int i = 0; i < 4; ++i)
#pragma unroll
    for (int j = 0; j < 4; ++j) acc[i][j] = (f32x4){0.f, 0.f, 0.f, 0.f};

  for (int k0 = 0; k0 < K; k0 += 32) {
#pragma unroll
    for (int p = 0; p < 2; ++p) {
      int row = wave * 32 + p * 16 + srow;
      int off = (wave * 2 + p) * 512;
      size_t ga = (size_t)(m0 + row) * K + k0 + kcol;
      g2l(Xh + ga, Ah + off);
      if (xlo) g2l(Xl + ga, Al + off);
      int n = n0 + row; if (n > N - 1) n = N - 1;
      size_t gb = (size_t)n * K + k0 + kcol;
      g2l(Wh + gb, Bh + off);
      if (wlo) g2l(Wl + gb, Bl + off);
    }
    __syncthreads();
    bf16x8 ah[4], bh[4];
#pragma unroll
    for (int i = 0; i < 4; ++i)
      ah[i] = *(const bf16x8*)(Ah + (size_t)(wr * 64 + i * 16 + lm) * 32 + lq * 8);
#pragma unroll
    for (int j = 0; j < 4; ++j)
      bh[j] = *(const bf16x8*)(Bh + (size_t)(wc * 64 + j * 16 + lm) * 32 + lq * 8);
#pragma unroll
    for (int i = 0; i < 4; ++i)
#pragma unroll
      for (int j = 0; j < 4; ++j)
        acc[i][j] = __builtin_amdgcn_mfma_f32_16x16x32_bf16(ah[i], bh[j], acc[i][j], 0, 0, 0);
    if (xlo) {
      bf16x8 al[4];
#pragma unroll
      for (int i = 0; i < 4; ++i)
        al[i] = *(const bf16x8*)(Al + (size_t)(wr * 64 + i * 16 + lm) * 32 + lq * 8);
#pragma unroll
      for (int i = 0; i < 4; ++i)
#pragma unroll
        for (int j = 0; j < 4; ++j)
          acc[i][j] = __builtin_amdgcn_mfma_f32_16x16x32_bf16(al[i], bh[j], acc[i][j], 0, 0, 0);
    }
    if (wlo) {
      bf16x8 bl[4];
#pragma unroll
      for (int j = 0; j < 4; ++j)
        bl[j] = *(const bf16x8*)(Bl + (size_t)(wc * 64 + j * 16 + lm) * 32 + lq * 8);
#pragma unroll
      for (int i = 0; i < 4; ++i)
#pragma unroll
        for (int j = 0; j < 4; ++j)
          acc[i][j] = __builtin_amdgcn_mfma_f32_16x16x32_bf16(ah[i], bl[j], acc[i][j], 0, 0, 0);
    }
    __syncthreads();
  }
#pragma unroll
  for (int i = 0; i < 4; ++i)
#pragma unroll
    for (int j = 0; j < 4; ++j) {
      int n = n0 + wc * 64 + j * 16 + lm;
      if (n >= N) continue;
      int mb = m0 + wr * 64 + i * 16 + lq * 4;
#pragma unroll
      for (int r = 0; r < 4; ++r) {
        float val = acc[i][j][r];
        size_t off = (size_t)(mb + r) * N + n;
        if (mode == 0) {
          ((float*)out)[off] = val;
        } else {
          if (mode == 2) val = tanhf(val);
          else if (mode == 3) val = 1.0f / (1.0f + __expf(-val));
          ((unsigned short*)out)[off] = f2bf(val);
        }
      }
    }
}

// ---------------- pre-scan fused elementwise ----------------
__global__ __launch_bounds__(256) void k_pre(
    const float* __restrict__ rp, const float* __restrict__ kp, float* __restrict__ vp,
    const unsigned short* __restrict__ ww, const unsigned short* __restrict__ aa,
    const unsigned short* __restrict__ vv,
    const float* __restrict__ vfirst,
    const float* __restrict__ w0, const float* __restrict__ a0, const float* __restrict__ v0,
    const float* __restrict__ kkc, const float* __restrict__ kac,
    const float* __restrict__ rkw,
    unsigned short* __restrict__ rb, unsigned short* __restrict__ wb,
    unsigned short* __restrict__ kb, unsigned short* __restrict__ vb,
    unsigned short* __restrict__ ab, unsigned short* __restrict__ bb,
    float* __restrict__ dp) {
  int gw = blockIdx.x * 4 + (threadIdx.x >> 6);
  int l = threadIdx.x & 63;
  int h = gw & (H_ - 1);
  size_t bt = (size_t)(gw >> 5);
  size_t idx = bt * C_ + h * 64 + l;
  int c = h * 64 + l;
  float rf = rp[idx], kf = kp[idx], vr = vp[idx];
  float z = -(w0[c] + bf2f(ww[idx]));
  float sp = (z > 15.f) ? z : log1pf(__expf(z));
  float wv = -sp - 0.5f;
  float ag = 1.f / (1.f + __expf(-(a0[c] + bf2f(aa[idx]))));
  float sv = 1.f / (1.f + __expf(-(v0[c] + bf2f(vv[idx]))));
  float vf = vr + (vfirst[idx] - vr) * sv;
  float kkv = kf * kkc[c];
  float ss = kkv * kkv;
#pragma unroll
  for (int m = 1; m < 64; m <<= 1) ss += __shfl_xor(ss, m);
  float nrm = fmaxf(sqrtf(ss), 1e-12f);
  float kkn = kkv / nrm;
  float ks = kf * (1.f + (ag - 1.f) * kac[c]);
  vp[idx] = vf;
  float bon = rf * ks * rkw[c];
#pragma unroll
  for (int m = 1; m < 64; m <<= 1) bon += __shfl_xor(bon, m);
  if (l == 0) dp[bt * H_ + h] = bon;
  rb[idx] = f2bf(rf); wb[idx] = f2bf(wv); kb[idx] = f2bf(ks);
  vb[idx] = f2bf(vf); ab[idx] = f2bf(-kkn); bb[idx] = f2bf(kkn * ag);
}

// ================= chunk-parallel scan =================
// Phase-split pipelined version. Exact per-step algebra:
//   P' = D_t P,  U' = D_t U + k_t v_t^T                       (phase A, no sa)
//   presums over P'/U' with raw weights a_{t+1} (for sa) and r_t (for z,y)
//   sa_{t+1} = sum(presum) + sa_t*(a_{t+1}.b_t);  z_t = sum + saP_t*(r_t.b_t);  y_t likewise
//   P = P' + b_t saP_t,  U = U' + b_t saU_t                   (phase B, 2 ops/row)
// The LDS reduce result is consumed one step late (scalar corrections carried),
// so the ds_read latency + reduce hides under ~170 independent phase-A instrs.
__global__ __launch_bounds__(256) void k_scanP(
    const unsigned short* __restrict__ rb,
    const unsigned short* __restrict__ wb, const unsigned short* __restrict__ kb,
    const unsigned short* __restrict__ vb, const unsigned short* __restrict__ ab,
    const unsigned short* __restrict__ bb,
    float* __restrict__ Pg, float* __restrict__ Ug,
    unsigned short* __restrict__ Zg, float* __restrict__ o) {
  const int blk = blockIdx.x;
  const int c = blk & (NC_ - 1), bh = blk >> 4;
  const int b = bh >> 5, h = bh & (H_ - 1);
  const int l = threadIdx.x & 63;
  const int kg = __builtin_amdgcn_readfirstlane(threadIdx.x >> 6);
  const int kg16 = kg * 16;
  __shared__ f32x4 part[2][256];
  size_t base = (size_t)b * ((size_t)T_ * C_) + (size_t)(c * L_) * C_ + h * 64 + l;
  size_t zbase = (size_t)blk * 8192;
  float P[16], U[16];
#pragma unroll
  for (int i = 0; i < 16; ++i) { P[i] = (kg16 + i == l) ? 1.f : 0.f; U[i] = 0.f; }
  float pr[4], pw[4], pk[4], pv[4], pb[4], pa[4];
#pragma unroll
  for (int s = 0; s < 4; ++s) {
    size_t a_ = base + (size_t)s * C_;
    pr[s] = bf2f(rb[a_]); pw[s] = bf2f(wb[a_]); pk[s] = bf2f(kb[a_]);
    pv[s] = bf2f(vb[a_]); pb[s] = bf2f(bb[a_]);
    pa[s] = bf2f(ab[base + (size_t)(s + 1) * C_]);  // a one step ahead
  }
  float a0l = bf2f(ab[base]);
  float saP = 0.f, saU = 0.f;
  float cP = 0.f, cU = 0.f, cZ = 0.f, cY = 0.f;
  for (int t0 = 0; t0 < L_; t0 += 4) {
#pragma unroll
    for (int u = 0; u < 4; ++u) {
      const int t = t0 + u;
      float rl_ = pr[u], wl = pw[u], kl = pk[u], vl = pv[u], bl = pb[u], al = pa[u];
      if (t + 4 < L_) {
        size_t a_ = base + (size_t)(t + 4) * C_;
        pr[u] = bf2f(rb[a_]); pw[u] = bf2f(wb[a_]); pk[u] = bf2f(kb[a_]);
        pv[u] = bf2f(vb[a_]); pb[u] = bf2f(bb[a_]);
        int ta = t + 5; if (ta > L_ - 1) ta = L_ - 1;   // value only feeds discarded sa_128
        pa[u] = bf2f(ab[base + (size_t)ta * C_]);
      }
      float ew = exp2f(wl * 1.4426950408889634f);
      // cross-lane dots for next-step corrections (uniform across wave)
      float dab = al * bl, drb = rl_ * bl;
#pragma unroll
      for (int m = 1; m < 64; m <<= 1) { dab += __shfl_xor(dab, m); drb += __shfl_xor(drb, m); }
      // phase A: scale + presums (independent of incoming sa)
      float pP = 0.f, pU = 0.f, zP = 0.f, yU = 0.f;
#pragma unroll
      for (int i = 0; i < 16; ++i) {
        int ki = kg16 + i;
        float ewk = rlane(ew, ki), kk = rlane(kl, ki);
        float Pp = P[i] * ewk;
        float Up = fmaf(U[i], ewk, kk * vl);
        P[i] = Pp; U[i] = Up;
        float ak = rlane(al, ki), rk = rlane(rl_, ki);
        pP = fmaf(ak, Pp, pP); zP = fmaf(rk, Pp, zP);
        pU = fmaf(ak, Up, pU); yU = fmaf(rk, Up, yU);
      }
      // consume last step's reduce (+ carried scalar corrections)
      if (t > 0) {
        f32x4 q0 = part[t & 1][l], q1 = part[t & 1][64 + l],
              q2 = part[t & 1][128 + l], q3 = part[t & 1][192 + l];
        saP = ((q0.x + q1.x) + (q2.x + q3.x)) + cP;
        saU = ((q0.y + q1.y) + (q2.y + q3.y)) + cU;
        if (kg == 0) {
          o[base + (size_t)(t - 1) * C_] = ((q0.w + q1.w) + (q2.w + q3.w)) + cY;
        } else if (kg == 1) {
          Zg[zbase + (t - 1) * 64 + l] = f2bf(((q0.z + q1.z) + (q2.z + q3.z)) + cZ);
        }
      } else {
        saP = a0l; saU = 0.f;
      }
      // phase B: rank-1 completion
#pragma unroll
      for (int i = 0; i < 16; ++i) {
        float bk = rlane(bl, kg16 + i);
        P[i] = fmaf(bk, saP, P[i]);
        U[i] = fmaf(bk, saU, U[i]);
      }
      cP = saP * dab; cU = saU * dab; cZ = saP * drb; cY = saU * drb;
      part[(t + 1) & 1][kg * 64 + l] = (f32x4){pP, pU, zP, yU};
      __syncthreads();
    }
  }
  // epilogue: finalize t = L_-1 outputs (parity (L_)&1 == 0)
  {
    f32x4 q0 = part[0][l], q1 = part[0][64 + l],
          q2 = part[0][128 + l], q3 = part[0][192 + l];
    if (kg == 0) {
      o[base + (size_t)(L_ - 1) * C_] = ((q0.w + q1.w) + (q2.w + q3.w)) + cY;
    } else if (kg == 1) {
      Zg[zbase + (L_ - 1) * 64 + l] = f2bf(((q0.z + q1.z) + (q2.z + q3.z)) + cZ);
    }
  }
  size_t pb_ = (size_t)blk * 4096;
#pragma unroll
  for (int i = 0; i < 16; ++i) {
    Pg[pb_ + (size_t)l * 64 + kg16 + i] = P[i];
    Ug[pb_ + (size_t)(kg16 + i) * 64 + l] = U[i];
  }
}

__global__ __launch_bounds__(256) void k_scanC(
    const float* __restrict__ Pg, const float* __restrict__ Ug,
    const float* __restrict__ s0, float* __restrict__ Scg, float* __restrict__ sout) {
  const int bh = blockIdx.x;
  const int l = threadIdx.x & 63;
  const int kg = __builtin_amdgcn_readfirstlane(threadIdx.x >> 6);
  const int kg16 = kg * 16;
  const int tid = threadIdx.x;
  __shared__ float Sb[4096];
#pragma unroll
  for (int q = 0; q < 4; ++q) {
    int e = tid * 16 + q * 4;
    *(f32x4*)(Sb + e) = *(const f32x4*)(s0 + (size_t)bh * 4096 + e);
  }
  __syncthreads();
  for (int c = 0; c < NC_; ++c) {
    size_t cb = ((size_t)bh * NC_ + c) * 4096;
#pragma unroll
    for (int q = 0; q < 4; ++q) {
      int e = tid * 16 + q * 4;
      *(f32x4*)(Scg + cb + e) = *(const f32x4*)(Sb + e);
    }
    const float* Pt = Pg + cb;
    const float* Uc = Ug + cb;
    float acc[16];
#pragma unroll
    for (int i = 0; i < 16; ++i) acc[i] = Uc[(size_t)(kg16 + i) * 64 + l];
    for (int j = 0; j < 64; ++j) {
      float s = Sb[j * 64 + l];
#pragma unroll
      for (int i = 0; i < 16; ++i) acc[i] = fmaf(Pt[j * 64 + kg16 + i], s, acc[i]);
    }
    __syncthreads();
#pragma unroll
    for (int i = 0; i < 16; ++i) Sb[(kg16 + i) * 64 + l] = acc[i];
    __syncthreads();
  }
#pragma unroll
  for (int q = 0; q < 4; ++q) {
    int e = tid * 16 + q * 4;
    *(f32x4*)(sout + (size_t)bh * 4096 + e) = *(const f32x4*)(Sb + e);
  }
}

// ---------------- apply chunk-start state: o += Z @ S0 (per chunk) ----------------
__global__ __launch_bounds__(256) void k_scanO(
    const unsigned short* __restrict__ Zg, const float* __restrict__ Scg,
    float* __restrict__ o) {
  const int blk = blockIdx.x;
  const int c = blk & (NC_ - 1), bh = blk >> 4;
  const int b = bh >> 5, h = bh & (H_ - 1);
  const int l = threadIdx.x & 63;
  const int w = threadIdx.x >> 6;
  float S[64];
  const float* Sp = Scg + (size_t)blk * 4096 + l;
#pragma unroll
  for (int k = 0; k < 64; ++k) S[k] = Sp[(size_t)k * 64];
  size_t zb = (size_t)blk * 8192;
  size_t ob = (size_t)b * ((size_t)T_ * C_) + (size_t)(c * L_) * C_ + h * 64 + l;
  for (int tt = 0; tt < 32; ++tt) {
    int t = w * 32 + tt;
    float zv = bf2f(Zg[zb + t * 64 + l]);  // lane l holds z_t[l]
    float a0_ = 0.f, a1_ = 0.f, a2_ = 0.f, a3_ = 0.f;
#pragma unroll
    for (int k = 0; k < 64; k += 4) {
      a0_ = fmaf(rlane(zv, k), S[k], a0_);
      a1_ = fmaf(rlane(zv, k + 1), S[k + 1], a1_);
      a2_ = fmaf(rlane(zv, k + 2), S[k + 2], a2_);
      a3_ = fmaf(rlane(zv, k + 3), S[k + 3], a3_);
    }
    o[ob + (size_t)t * C_] += (a0_ + a1_) + (a2_ + a3_);
  }
}

// ---------------- post-scan: GroupNorm + bonus + *g -> bf16 ----------------
__global__ __launch_bounds__(256) void k_post(
    const float* __restrict__ o, const float* __restrict__ vp, const float* __restrict__ gp,
    const float* __restrict__ dp,
    const float* __restrict__ lnw, const float* __restrict__ lnb,
    unsigned short* __restrict__ z) {
  int gw = blockIdx.x * 4 + (threadIdx.x >> 6);
  int l = threadIdx.x & 63;
  int h = gw & (H_ - 1);
  size_t bt = (size_t)(gw >> 5);
  size_t idx = bt * C_ + h * 64 + l;
  int c = h * 64 + l;
  float ov = o[idx];
  float s1 = ov;
#pragma unroll
  for (int m = 1; m < 64; m <<= 1) s1 += __shfl_xor(s1, m);
  float mu = s1 * (1.f / 64.f);
  float d = ov - mu;
  float s2 = d * d;
#pragma unroll
  for (int m = 1; m < 64; m <<= 1) s2 += __shfl_xor(s2, m);
  float var = s2 * (1.f / 64.f);
  float y = d * rsqrtf(var + 6.4e-4f);
  y = y * lnw[c] + lnb[c];
  y = fmaf(dp[bt * H_ + h], vp[idx], y);
  z[idx] = f2bf(y * gp[idx]);
}

extern "C" void kernel_launch(void* const* d_in, const int* in_sizes, int n_in,
                              void* d_out, int out_size, void* d_ws, size_t ws_size,
                              hipStream_t stream) {
  const float* x      = (const float*)d_in[0];
  const float* shift  = (const float*)d_in[1];
  const float* wkv    = (const float*)d_in[2];
  const float* vfirst = (const float*)d_in[3];
  const float* x_r    = (const float*)d_in[4];
  const float* x_w    = (const float*)d_in[5];
  const float* x_k    = (const float*)d_in[6];
  const float* x_v    = (const float*)d_in[7];
  const float* x_a    = (const float*)d_in[8];
  const float* x_g    = (const float*)d_in[9];
  const float* w0     = (const float*)d_in[10];
  const float* w1     = (const float*)d_in[11];
  const float* w2     = (const float*)d_in[12];
  const float* a0     = (const float*)d_in[13];
  const float* a1     = (const float*)d_in[14];
  const float* a2     = (const float*)d_in[15];
  const float* v0     = (const float*)d_in[16];
  const float* v1     = (const float*)d_in[17];
  const float* v2     = (const float*)d_in[18];
  const float* g1     = (const float*)d_in[19];
  const float* g2     = (const float*)d_in[20];
  const float* k_k    = (const float*)d_in[21];
  const float* k_a    = (const float*)d_in[22];
  const float* r_k    = (const float*)d_in[23];
  const float* W_r    = (const float*)d_in[24];
  const float* W_k    = (const float*)d_in[25];
  const float* W_v    = (const float*)d_in[26];
  const float* W_o    = (const float*)d_in[27];
  const float* ln_w   = (const float*)d_in[28];
  const float* ln_b   = (const float*)d_in[29];

  // ---- workspace plan: ~213 MiB (footprint identical to passing version) ----
  char* wp = (char*)d_ws;
  auto alloc = [&](size_t bytes) { char* p = wp; wp += (bytes + 255) & ~(size_t)255; return p; };
  const size_t SB = BTC_ * 2;
  const size_t SF = BTC_ * 4;

  unsigned short* w1t = (unsigned short*)alloc((size_t)C_ * 64 * 2);
  unsigned short* w2t = (unsigned short*)alloc((size_t)C_ * 64 * 2);
  unsigned short* a1t = (unsigned short*)alloc((size_t)C_ * 64 * 2);
  unsigned short* a2t = (unsigned short*)alloc((size_t)C_ * 64 * 2);
  unsigned short* v1t = (unsigned short*)alloc((size_t)C_ * 32 * 2);
  unsigned short* v2t = (unsigned short*)alloc((size_t)C_ * 32 * 2);
  unsigned short* g1t = (unsigned short*)alloc((size_t)C_ * 128 * 2);
  unsigned short* g2t = (unsigned short*)alloc((size_t)C_ * 128 * 2);
  unsigned short* hw  = (unsigned short*)alloc((size_t)BT_ * 64 * 2);
  unsigned short* ha  = (unsigned short*)alloc((size_t)BT_ * 64 * 2);
  unsigned short* hv  = (unsigned short*)alloc((size_t)BT_ * 32 * 2);
  unsigned short* hg  = (unsigned short*)alloc((size_t)BT_ * 128 * 2);
  unsigned short* Wt2 = (unsigned short*)alloc((size_t)C_ * C_ * 2 * 2); // hi|lo; later Zg (bf16)
  float* dp           = (float*)alloc((size_t)BT_ * H_ * 4);
  unsigned short* xw  = (unsigned short*)alloc(SB);      // mix-w -> wb -> Scg (f32)
  unsigned short* xa  = (unsigned short*)alloc(SB);
  unsigned short* xg  = (unsigned short*)alloc(SB);
  unsigned short* xr2 = (unsigned short*)alloc(2 * SB); // -> kbuf f32 -> Pg|Ug -> zbuf
  unsigned short* xk2 = (unsigned short*)alloc(2 * SB); // -> vbuf f32
  unsigned short* xv2 = (unsigned short*)alloc(2 * SB); // -> scan rb|kb
  float* rbuf         = (float*)alloc(SF);              // r f32 -> g f32
  unsigned short* vbb = (unsigned short*)alloc(SB);

  unsigned short* Wh = Wt2;
  unsigned short* Wl = Wt2 + (size_t)C_ * C_;
  unsigned short* xr_h = xr2, *xr_l = xr2 + BTC_;
  unsigned short* xk_h = xk2, *xk_l = xk2 + BTC_;
  unsigned short* xv_h = xv2, *xv_l = xv2 + BTC_;
  float* kbuf = (float*)xr2;
  float* vbuf = (float*)xk2;
  unsigned short* rb = xv2;
  unsigned short* kb = xv2 + BTC_;
  float* gfull = rbuf;
  unsigned short* zbuf = (unsigned short*)xr2;
  float* Pg  = (float*)xr2;
  float* Ug  = Pg + (size_t)1024 * 4096;
  unsigned short* zg = Wt2;          // bf16 z-coefficients, 16 MiB (Wt2 dead here)
  float* Scg = (float*)xw;           // chunk-start states, 16 MiB (wb dead after scanP)

  float* outp  = (float*)d_out;
  float* xlast = outp + BTC_;
  float* soutp = outp + BTC_ + (size_t)B_ * C_;
  float* obuf  = outp;

  auto tr = [&](const float* in, unsigned short* out, int R, int Cc) {
    k_tr<<<dim3(Cc / 32, R / 32), 256, 0, stream>>>(in, out, R, Cc);
  };
  auto gemm = [&](const unsigned short* X, const unsigned short* Wtp, void* out,
                  int M, int N, int K, int mode) {
    k_gemm<<<dim3((N + 127) / 128, M / 128), 256, 0, stream>>>(X, Wtp, out, M, N, K, mode);
  };
  auto gemm2 = [&](const unsigned short* Xh_, const unsigned short* Xl_, int xlo,
                   const unsigned short* Wh_, const unsigned short* Wl_, int wlo,
                   void* out, int M, int N, int K, int mode) {
    k_gemm2<<<dim3((N + 127) / 128, M / 128), 256, 0, stream>>>(Xh_, Xl_, xlo, Wh_, Wl_, wlo,
                                                                out, M, N, K, mode);
  };

  k_mix<<<(int)(BTC_ / 4 / 256), 256, 0, stream>>>(x, shift, x_r, x_w, x_k, x_v, x_a, x_g,
                                                   xr_h, xr_l, xk_h, xk_l, xv_h, xv_l,
                                                   xw, xa, xg, xlast);
  tr(w1, w1t, C_, 64);  tr(w2, w2t, 64, C_);
  tr(a1, a1t, C_, 64);  tr(a2, a2t, 64, C_);
  tr(v1, v1t, C_, 32);  tr(v2, v2t, 32, C_);
  tr(g1, g1t, C_, 128); tr(g2, g2t, 128, C_);

  // LoRA stage 1
  gemm(xw, w1t, hw, BT_, 64, C_, 2);
  gemm(xa, a1t, ha, BT_, 64, C_, 1);
  gemm2(xv_h, xv_l, 1, v1t, nullptr, 0, hv, BT_, 32, C_, 1);
  gemm(xg, g1t, hg, BT_, 128, C_, 3);

  // big projections, split precision (hh + lh + hl)
  k_trs<<<dim3(C_ / 32, C_ / 32), 256, 0, stream>>>(W_r, Wh, Wl, C_, C_);
  gemm2(xr_h, xr_l, 1, Wh, Wl, 1, rbuf, BT_, C_, C_, 0);
  k_trs<<<dim3(C_ / 32, C_ / 32), 256, 0, stream>>>(W_k, Wh, Wl, C_, C_);
  gemm2(xk_h, xk_l, 1, Wh, Wl, 1, kbuf, BT_, C_, C_, 0);
  k_trs<<<dim3(C_ / 32, C_ / 32), 256, 0, stream>>>(W_v, Wh, Wl, C_, C_);
  gemm2(xv_h, xv_l, 1, Wh, Wl, 1, vbuf, BT_, C_, C_, 0);

  // LoRA stage 2 into dead mix buffers
  gemm(hw, w2t, xw, BT_, C_, 64, 1);
  gemm(ha, a2t, xa, BT_, C_, 64, 1);
  gemm(hv, v2t, xg, BT_, C_, 32, 1);

  k_pre<<<BT_ * H_ / 4, 256, 0, stream>>>(rbuf, kbuf, vbuf, xw, xa, xg, vfirst,
                                          w0, a0, v0, k_k, k_a, r_k,
                                          rb, xw, kb, vbb, xa, xg, dp);

  gemm(hg, g2t, gfull, BT_, C_, 128, 0);

  // chunk-parallel scan: P/U/z/y in one pass, combine, then apply S0 (no replay)
  k_scanP<<<B_ * H_ * NC_, 256, 0, stream>>>(rb, xw, kb, vbb, xa, xg, Pg, Ug, zg, obuf);
  k_scanC<<<B_ * H_, 256, 0, stream>>>(Pg, Ug, wkv, Scg, soutp);
  k_scanO<<<B_ * H_ * NC_, 256, 0, stream>>>(zg, Scg, obuf);

  k_post<<<BT_ * H_ / 4, 256, 0, stream>>>(obuf, vbuf, gfull, dp, ln_w, ln_b, zbuf);

  tr(W_o, Wh, C_, C_);
  gemm(zbuf, Wh, outp, BT_, C_, C_, 0);
}

// Round 3
// 1408.427 us; speedup vs baseline: 1.1799x; 1.1799x over previous
//
#include <hip/hip_runtime.h>
#include <cstdint>
#include <cmath>

#define B_ 2
#define T_ 2048
#define C_ 2048
#define H_ 32
#define BT_ (B_ * T_)
#define BTC_ ((size_t)B_ * T_ * C_)
#define L_ 128
#define NC_ 16

typedef __attribute__((ext_vector_type(4))) float f32x4;
typedef __attribute__((ext_vector_type(2))) float f32x2;
typedef __attribute__((ext_vector_type(8))) short bf16x8;
typedef __attribute__((ext_vector_type(4))) unsigned short us4;
typedef __attribute__((ext_vector_type(4))) int i32x4;

__device__ __forceinline__ unsigned short f2bf(float f) {
  union { float f; unsigned int u; } c; c.f = f;
  unsigned int u = c.u;
  return (unsigned short)((u + 0x7FFFu + ((u >> 16) & 1u)) >> 16);
}
__device__ __forceinline__ float bf2f(unsigned short h) {
  union { unsigned int u; float f; } c; c.u = ((unsigned int)h) << 16;
  return c.f;
}
__device__ __forceinline__ float rlane(float v, int lane) {
  return __int_as_float(__builtin_amdgcn_readlane(__float_as_int(v), lane));
}
__device__ __forceinline__ void split4(f32x4 v, us4& h, us4& l) {
  h.x = f2bf(v.x); l.x = f2bf(v.x - bf2f(h.x));
  h.y = f2bf(v.y); l.y = f2bf(v.y - bf2f(h.y));
  h.z = f2bf(v.z); l.z = f2bf(v.z - bf2f(h.z));
  h.w = f2bf(v.w); l.w = f2bf(v.w - bf2f(h.w));
}
// async global->LDS, 16 B per lane; LDS dest = wave-uniform base + lane*16
__device__ __forceinline__ void g2l(const void* g, void* l) {
  __builtin_amdgcn_global_load_lds((const __attribute__((address_space(1))) void*)g,
                                   (__attribute__((address_space(3))) void*)l, 16, 0, 0);
}

// ---------------- token shift + mixes: r/k/v as bf16 hi+lo pairs, w/a/g bf16 ----------------
__global__ __launch_bounds__(256) void k_mix(
    const float* __restrict__ x, const float* __restrict__ shift,
    const float* __restrict__ m_r, const float* __restrict__ m_w,
    const float* __restrict__ m_k, const float* __restrict__ m_v,
    const float* __restrict__ m_a, const float* __restrict__ m_g,
    unsigned short* __restrict__ r_h, unsigned short* __restrict__ r_l,
    unsigned short* __restrict__ k_h, unsigned short* __restrict__ k_l,
    unsigned short* __restrict__ v_h, unsigned short* __restrict__ v_l,
    unsigned short* __restrict__ o_w, unsigned short* __restrict__ o_a,
    unsigned short* __restrict__ o_g,
    float* __restrict__ xlast) {
  size_t i4 = ((size_t)blockIdx.x * 256 + threadIdx.x) * 4;
  int c = (int)(i4 % C_);
  size_t bt = i4 / C_;
  int t = (int)(bt % T_);
  int b = (int)(bt / T_);
  f32x4 xv = *(const f32x4*)(x + i4);
  f32x4 pv = (t == 0) ? *(const f32x4*)(shift + (size_t)b * C_ + c)
                      : *(const f32x4*)(x + i4 - C_);
  f32x4 dx = pv - xv;
#define MIXHL(mp, oh, ol) { f32x4 mm = *(const f32x4*)(mp + c); f32x4 rr = xv + dx * mm; \
    us4 hh, ll; split4(rr, hh, ll); *(us4*)(oh + i4) = hh; *(us4*)(ol + i4) = ll; }
#define MIXH(mp, oh) { f32x4 mm = *(const f32x4*)(mp + c); f32x4 rr = xv + dx * mm; \
    us4 pk; pk.x = f2bf(rr.x); pk.y = f2bf(rr.y); pk.z = f2bf(rr.z); pk.w = f2bf(rr.w); \
    *(us4*)(oh + i4) = pk; }
  MIXHL(m_r, r_h, r_l) MIXHL(m_k, k_h, k_l) MIXHL(m_v, v_h, v_l)
  MIXH(m_w, o_w) MIXH(m_a, o_a) MIXH(m_g, o_g)
#undef MIXHL
#undef MIXH
  if (t == T_ - 1) *(f32x4*)(xlast + (size_t)b * C_ + c) = xv;
}

// ---------------- f32 [R][Cc] -> bf16 [Cc][R] transpose ----------------
__global__ __launch_bounds__(256) void k_tr(const float* __restrict__ in,
                                            unsigned short* __restrict__ out,
                                            int R, int Cc) {
  __shared__ float tile[32][33];
  int c0 = blockIdx.x * 32, r0 = blockIdx.y * 32;
  int tid = threadIdx.x;
  int rr = tid >> 3, c4 = (tid & 7) * 4;
  f32x4 v = *(const f32x4*)(in + (size_t)(r0 + rr) * Cc + c0 + c4);
  tile[rr][c4] = v.x; tile[rr][c4 + 1] = v.y; tile[rr][c4 + 2] = v.z; tile[rr][c4 + 3] = v.w;
  __syncthreads();
  int cc = tid >> 3, r4 = (tid & 7) * 4;
  us4 o;
  o.x = f2bf(tile[r4][cc]); o.y = f2bf(tile[r4 + 1][cc]);
  o.z = f2bf(tile[r4 + 2][cc]); o.w = f2bf(tile[r4 + 3][cc]);
  *(us4*)(out + (size_t)(c0 + cc) * R + r0 + r4) = o;
}

// ---------------- f32 [R][Cc] -> bf16 hi+lo [Cc][R] split transpose ----------------
__global__ __launch_bounds__(256) void k_trs(const float* __restrict__ in,
                                             unsigned short* __restrict__ oh,
                                             unsigned short* __restrict__ ol,
                                             int R, int Cc) {
  __shared__ float tile[32][33];
  int c0 = blockIdx.x * 32, r0 = blockIdx.y * 32;
  int tid = threadIdx.x;
  int rr = tid >> 3, c4 = (tid & 7) * 4;
  f32x4 v = *(const f32x4*)(in + (size_t)(r0 + rr) * Cc + c0 + c4);
  tile[rr][c4] = v.x; tile[rr][c4 + 1] = v.y; tile[rr][c4 + 2] = v.z; tile[rr][c4 + 3] = v.w;
  __syncthreads();
  int cc = tid >> 3, r4 = (tid & 7) * 4;
  f32x4 w = { tile[r4][cc], tile[r4 + 1][cc], tile[r4 + 2][cc], tile[r4 + 3][cc] };
  us4 h, l; split4(w, h, l);
  size_t o = (size_t)(c0 + cc) * R + r0 + r4;
  *(us4*)(oh + o) = h; *(us4*)(ol + o) = l;
}

// ---------------- bf16 GEMM: C[M,N] = X[M,K] @ Wt[N,K]^T (global_load_lds staging) ----------------
// XCD-aware bijective block swizzle (T1): all launch grids have nwg % 8 == 0.
__global__ __launch_bounds__(256) void k_gemm(
    const unsigned short* __restrict__ X, const unsigned short* __restrict__ Wt,
    void* __restrict__ out, int M, int N, int K, int mode) {
  __shared__ alignas(16) unsigned short As[128 * 32];
  __shared__ alignas(16) unsigned short Bs[128 * 32];
  const int tid = threadIdx.x;
  const int lane = tid & 63, wave = tid >> 6;
  const int wr = wave >> 1, wc = wave & 1;
  const int lm = lane & 15, lq = lane >> 4;
  const int gx = gridDim.x;
  const int nwg = gx * gridDim.y;
  const int bid = blockIdx.y * gx + blockIdx.x;
  const int sz = (bid & 7) * (nwg >> 3) + (bid >> 3);
  const int m0 = (sz / gx) * 128, n0 = (sz % gx) * 128;
  const int srow = (lane >> 2);
  const int kcol = (lane & 3) * 8;
  f32x4 acc[4][4];
#pragma unroll
  for (int i = 0; i < 4; ++i)
#pragma unroll
    for (int j = 0; j < 4; ++j) acc[i][j] = (f32x4){0.f, 0.f, 0.f, 0.f};

  for (int k0 = 0; k0 < K; k0 += 32) {
#pragma unroll
    for (int p = 0; p < 2; ++p) {
      int row = wave * 32 + p * 16 + srow;
      g2l(X + (size_t)(m0 + row) * K + k0 + kcol, As + (wave * 2 + p) * 512);
      int n = n0 + row; if (n > N - 1) n = N - 1;
      g2l(Wt + (size_t)n * K + k0 + kcol, Bs + (wave * 2 + p) * 512);
    }
    __syncthreads();
    bf16x8 af[4], bfr[4];
#pragma unroll
    for (int i = 0; i < 4; ++i)
      af[i] = *(const bf16x8*)(As + (size_t)(wr * 64 + i * 16 + lm) * 32 + lq * 8);
#pragma unroll
    for (int j = 0; j < 4; ++j)
      bfr[j] = *(const bf16x8*)(Bs + (size_t)(wc * 64 + j * 16 + lm) * 32 + lq * 8);
#pragma unroll
    for (int i = 0; i < 4; ++i)
#pragma unroll
      for (int j = 0; j < 4; ++j)
        acc[i][j] = __builtin_amdgcn_mfma_f32_16x16x32_bf16(af[i], bfr[j], acc[i][j], 0, 0, 0);
    __syncthreads();
  }
#pragma unroll
  for (int i = 0; i < 4; ++i)
#pragma unroll
    for (int j = 0; j < 4; ++j) {
      int n = n0 + wc * 64 + j * 16 + lm;
      if (n >= N) continue;
      int mb = m0 + wr * 64 + i * 16 + lq * 4;
#pragma unroll
      for (int r = 0; r < 4; ++r) {
        float val = acc[i][j][r];
        size_t off = (size_t)(mb + r) * N + n;
        if (mode == 0) {
          ((float*)out)[off] = val;
        } else {
          if (mode == 2) val = tanhf(val);
          else if (mode == 3) val = 1.0f / (1.0f + __expf(-val));
          ((unsigned short*)out)[off] = f2bf(val);
        }
      }
    }
}

// ---------------- split (hi+lo) bf16 GEMM: hh + lh + hl (ll dropped, ~2^-17 rel) ----------------
__global__ __launch_bounds__(256) void k_gemm2(
    const unsigned short* __restrict__ Xh, const unsigned short* __restrict__ Xl, int xlo,
    const unsigned short* __restrict__ Wh, const unsigned short* __restrict__ Wl, int wlo,
    void* __restrict__ out, int M, int N, int K, int mode) {
  __shared__ alignas(16) unsigned short Ah[128 * 32];
  __shared__ alignas(16) unsigned short Al[128 * 32];
  __shared__ alignas(16) unsigned short Bh[128 * 32];
  __shared__ alignas(16) unsigned short Bl[128 * 32];
  const int tid = threadIdx.x;
  const int lane = tid & 63, wave = tid >> 6;
  const int wr = wave >> 1, wc = wave & 1;
  const int lm = lane & 15, lq = lane >> 4;
  const int gx = gridDim.x;
  const int nwg = gx * gridDim.y;
  const int bid = blockIdx.y * gx + blockIdx.x;
  const int sz = (bid & 7) * (nwg >> 3) + (bid >> 3);
  const int m0 = (sz / gx) * 128, n0 = (sz % gx) * 128;
  const int srow = (lane >> 2);
  const int kcol = (lane & 3) * 8;
  f32x4 acc[4][4];
#pragma unroll
  for (int i = 0; i < 4; ++i)
#pragma unroll
    for (int j = 0; j < 4; ++j) acc[i][j] = (f32x4){0.f, 0.f, 0.f, 0.f};

  for (int k0 = 0; k0 < K; k0 += 32) {
#pragma unroll
    for (int p = 0; p < 2; ++p) {
      int row = wave * 32 + p * 16 + srow;
      int off = (wave * 2 + p) * 512;
      size_t ga = (size_t)(m0 + row) * K + k0 + kcol;
      g2l(Xh + ga, Ah + off);
      if (xlo) g2l(Xl + ga, Al + off);
      int n = n0 + row; if (n > N - 1) n = N - 1;
      size_t gb = (size_t)n * K + k0 + kcol;
      g2l(Wh + gb, Bh + off);
      if (wlo) g2l(Wl + gb, Bl + off);
    }
    __syncthreads();
    bf16x8 ah[4], bh[4];
#pragma unroll
    for (int i = 0; i < 4; ++i)
      ah[i] = *(const bf16x8*)(Ah + (size_t)(wr * 64 + i * 16 + lm) * 32 + lq * 8);
#pragma unroll
    for (int j = 0; j < 4; ++j)
      bh[j] = *(const bf16x8*)(Bh + (size_t)(wc * 64 + j * 16 + lm) * 32 + lq * 8);
#pragma unroll
    for (int i = 0; i < 4; ++i)
#pragma unroll
      for (int j = 0; j < 4; ++j)
        acc[i][j] = __builtin_amdgcn_mfma_f32_16x16x32_bf16(ah[i], bh[j], acc[i][j], 0, 0, 0);
    if (xlo) {
      bf16x8 al[4];
#pragma unroll
      for (int i = 0; i < 4; ++i)
        al[i] = *(const bf16x8*)(Al + (size_t)(wr * 64 + i * 16 + lm) * 32 + lq * 8);
#pragma unroll
      for (int i = 0; i < 4; ++i)
#pragma unroll
        for (int j = 0; j < 4; ++j)
          acc[i][j] = __builtin_amdgcn_mfma_f32_16x16x32_bf16(al[i], bh[j], acc[i][j], 0, 0, 0);
    }
    if (wlo) {
      bf16x8 bl[4];
#pragma unroll
      for (int j = 0; j < 4; ++j)
        bl[j] = *(const bf16x8*)(Bl + (size_t)(wc * 64 + j * 16 + lm) * 32 + lq * 8);
#pragma unroll
      for (int i = 0; i < 4; ++i)
#pragma unroll
        for (int j = 0; j < 4; ++j)
          acc[i][j] = __builtin_amdgcn_mfma_f32_16x16x32_bf16(ah[i], bl[j], acc[i][j], 0, 0, 0);
    }
    __syncthreads();
  }
#pragma unroll
  for (int i = 0; i < 4; ++i)
#pragma unroll
    for (int j = 0; j < 4; ++j) {
      int n = n0 + wc * 64 + j * 16 + lm;
      if (n >= N) continue;
      int mb = m0 + wr * 64 + i * 16 + lq * 4;
#pragma unroll
      for (int r = 0; r < 4; ++r) {
        float val = acc[i][j][r];
        size_t off = (size_t)(mb + r) * N + n;
        if (mode == 0) {
          ((float*)out)[off] = val;
        } else {
          if (mode == 2) val = tanhf(val);
          else if (mode == 3) val = 1.0f / (1.0f + __expf(-val));
          ((unsigned short*)out)[off] = f2bf(val);
        }
      }
    }
}

// ---------------- pre-scan fused elementwise ----------------
__global__ __launch_bounds__(256) void k_pre(
    const float* __restrict__ rp, const float* __restrict__ kp, float* __restrict__ vp,
    const unsigned short* __restrict__ ww, const unsigned short* __restrict__ aa,
    const unsigned short* __restrict__ vv,
    const float* __restrict__ vfirst,
    const float* __restrict__ w0, const float* __restrict__ a0, const float* __restrict__ v0,
    const float* __restrict__ kkc, const float* __restrict__ kac,
    const float* __restrict__ rkw,
    unsigned short* __restrict__ rb, unsigned short* __restrict__ wb,
    unsigned short* __restrict__ kb, unsigned short* __restrict__ vb,
    unsigned short* __restrict__ ab, unsigned short* __restrict__ bb,
    float* __restrict__ dp) {
  int gw = blockIdx.x * 4 + (threadIdx.x >> 6);
  int l = threadIdx.x & 63;
  int h = gw & (H_ - 1);
  size_t bt = (size_t)(gw >> 5);
  size_t idx = bt * C_ + h * 64 + l;
  int c = h * 64 + l;
  float rf = rp[idx], kf = kp[idx], vr = vp[idx];
  float z = -(w0[c] + bf2f(ww[idx]));
  float sp = (z > 15.f) ? z : log1pf(__expf(z));
  float wv = -sp - 0.5f;
  float ag = 1.f / (1.f + __expf(-(a0[c] + bf2f(aa[idx]))));
  float sv = 1.f / (1.f + __expf(-(v0[c] + bf2f(vv[idx]))));
  float vf = vr + (vfirst[idx] - vr) * sv;
  float kkv = kf * kkc[c];
  float ss = kkv * kkv;
#pragma unroll
  for (int m = 1; m < 64; m <<= 1) ss += __shfl_xor(ss, m);
  float nrm = fmaxf(sqrtf(ss), 1e-12f);
  float kkn = kkv / nrm;
  float ks = kf * (1.f + (ag - 1.f) * kac[c]);
  vp[idx] = vf;
  float bon = rf * ks * rkw[c];
#pragma unroll
  for (int m = 1; m < 64; m <<= 1) bon += __shfl_xor(bon, m);
  if (l == 0) dp[bt * H_ + h] = bon;
  rb[idx] = f2bf(rf); wb[idx] = f2bf(wv); kb[idx] = f2bf(ks);
  vb[idx] = f2bf(vf); ab[idx] = f2bf(-kkn); bb[idx] = f2bf(kkn * ag);
}

// ================= chunk-parallel scan: ONE WAVE PER CHUNK =================
// Lane l owns column l of the full 64x64 chunk state: P[k] = A_t[k][l],
// U[k] = U_t[k][l] in registers. The sa = a^T S reduce is an in-wave
// readlane reduce -> zero barriers, zero LDS, zero cross-lane shuffles.
// Per step (fused single k-loop):
//   P[k] = ew[k]*P[k] + b[k]*saP ; U[k] = ew[k]*U[k] + b[k]*saU + k[k]*v[l]
//   z_t[l] = sum_k r[k] P[k] ; y_t[l] = sum_k r[k] U[k]   (o = y, Zg = z)
//   saP' = sum_k a_{t+1}[k] P[k] ; saU' likewise          (next-step sa)
__global__ __launch_bounds__(64) void k_scanP(
    const unsigned short* __restrict__ rb,
    const unsigned short* __restrict__ wb, const unsigned short* __restrict__ kb,
    const unsigned short* __restrict__ vb, const unsigned short* __restrict__ ab,
    const unsigned short* __restrict__ bb,
    float* __restrict__ Pg, float* __restrict__ Ug,
    unsigned short* __restrict__ Zg, float* __restrict__ o) {
  const int blk = blockIdx.x;
  const int c = blk & (NC_ - 1), bh = blk >> 4;
  const int b = bh >> 5, h = bh & (H_ - 1);
  const int l = threadIdx.x & 63;
  size_t base = (size_t)b * ((size_t)T_ * C_) + (size_t)(c * L_) * C_ + h * 64 + l;
  size_t zbase = (size_t)blk * 8192;
  float P[64], U[64];
#pragma unroll
  for (int k = 0; k < 64; ++k) { P[k] = (k == l) ? 1.f : 0.f; U[k] = 0.f; }
  float pr[4], pw[4], pk[4], pv[4], pb[4], pa[4];
#pragma unroll
  for (int s = 0; s < 4; ++s) {
    size_t a_ = base + (size_t)s * C_;
    pr[s] = bf2f(rb[a_]); pw[s] = bf2f(wb[a_]); pk[s] = bf2f(kb[a_]);
    pv[s] = bf2f(vb[a_]); pb[s] = bf2f(bb[a_]);
    pa[s] = bf2f(ab[base + (size_t)(s + 1) * C_]);  // a one step ahead
  }
  // t=0: sa over A=I, U=0  ->  saP = a_0[l] (lane-local), saU = 0
  float saP = bf2f(ab[base]), saU = 0.f;
  for (int t0 = 0; t0 < L_; t0 += 4) {
#pragma unroll
    for (int u = 0; u < 4; ++u) {
      const int t = t0 + u;
      float rl_ = pr[u], wl = pw[u], kl = pk[u], vl = pv[u], bl = pb[u], al = pa[u];
      if (t + 4 < L_) {
        size_t a_ = base + (size_t)(t + 4) * C_;
        pr[u] = bf2f(rb[a_]); pw[u] = bf2f(wb[a_]); pk[u] = bf2f(kb[a_]);
        pv[u] = bf2f(vb[a_]); pb[u] = bf2f(bb[a_]);
        int ta = t + 5; if (ta > L_ - 1) ta = L_ - 1;  // clamped value only feeds discarded sa_L
        pa[u] = bf2f(ab[base + (size_t)ta * C_]);
      }
      float ew = exp2f(wl * 1.4426950408889634f);
      float zz0 = 0.f, zz1 = 0.f, zz2 = 0.f, zz3 = 0.f;
      float yy0 = 0.f, yy1 = 0.f, yy2 = 0.f, yy3 = 0.f;
      float qp0 = 0.f, qp1 = 0.f, qp2 = 0.f, qp3 = 0.f;
      float qu0 = 0.f, qu1 = 0.f, qu2 = 0.f, qu3 = 0.f;
#pragma unroll
      for (int k = 0; k < 64; k += 4) {
#define STEPK(kk, ZZ, YY, QP, QU)                                        \
        {                                                                \
          float s_ew = rlane(ew, kk), s_b = rlane(bl, kk),               \
                s_k = rlane(kl, kk);                                     \
          float Pn = fmaf(P[kk], s_ew, s_b * saP);                       \
          float Un = fmaf(U[kk], s_ew, fmaf(s_b, saU, s_k * vl));        \
          P[kk] = Pn; U[kk] = Un;                                        \
          float s_r = rlane(rl_, kk), s_a = rlane(al, kk);               \
          ZZ = fmaf(s_r, Pn, ZZ); YY = fmaf(s_r, Un, YY);                \
          QP = fmaf(s_a, Pn, QP); QU = fmaf(s_a, Un, QU);                \
        }
        STEPK(k,     zz0, yy0, qp0, qu0)
        STEPK(k + 1, zz1, yy1, qp1, qu1)
        STEPK(k + 2, zz2, yy2, qp2, qu2)
        STEPK(k + 3, zz3, yy3, qp3, qu3)
#undef STEPK
      }
      o[base + (size_t)t * C_] = (yy0 + yy1) + (yy2 + yy3);
      Zg[zbase + t * 64 + l] = f2bf((zz0 + zz1) + (zz2 + zz3));
      saP = (qp0 + qp1) + (qp2 + qp3);
      saU = (qu0 + qu1) + (qu2 + qu3);
    }
  }
  size_t pb_ = (size_t)blk * 4096;
#pragma unroll
  for (int k4 = 0; k4 < 64; k4 += 4) {
    f32x4 pv4 = { P[k4], P[k4 + 1], P[k4 + 2], P[k4 + 3] };
    *(f32x4*)(Pg + pb_ + (size_t)l * 64 + k4) = pv4;
  }
#pragma unroll
  for (int k = 0; k < 64; ++k) Ug[pb_ + (size_t)k * 64 + l] = U[k];
}

__global__ __launch_bounds__(256) void k_scanC(
    const float* __restrict__ Pg, const float* __restrict__ Ug,
    const float* __restrict__ s0, float* __restrict__ Scg, float* __restrict__ sout) {
  const int bh = blockIdx.x;
  const int l = threadIdx.x & 63;
  const int kg = __builtin_amdgcn_readfirstlane(threadIdx.x >> 6);
  const int kg16 = kg * 16;
  const int tid = threadIdx.x;
  __shared__ float Sb[4096];
#pragma unroll
  for (int q = 0; q < 4; ++q) {
    int e = tid * 16 + q * 4;
    *(f32x4*)(Sb + e) = *(const f32x4*)(s0 + (size_t)bh * 4096 + e);
  }
  __syncthreads();
  for (int c = 0; c < NC_; ++c) {
    size_t cb = ((size_t)bh * NC_ + c) * 4096;
#pragma unroll
    for (int q = 0; q < 4; ++q) {
      int e = tid * 16 + q * 4;
      *(f32x4*)(Scg + cb + e) = *(const f32x4*)(Sb + e);
    }
    const float* Pt = Pg + cb;
    const float* Uc = Ug + cb;
    float acc[16];
#pragma unroll
    for (int i = 0; i < 16; ++i) acc[i] = Uc[(size_t)(kg16 + i) * 64 + l];
    for (int j = 0; j < 64; ++j) {
      float s = Sb[j * 64 + l];
#pragma unroll
      for (int i = 0; i < 16; ++i) acc[i] = fmaf(Pt[j * 64 + kg16 + i], s, acc[i]);
    }
    __syncthreads();
#pragma unroll
    for (int i = 0; i < 16; ++i) Sb[(kg16 + i) * 64 + l] = acc[i];
    __syncthreads();
  }
#pragma unroll
  for (int q = 0; q < 4; ++q) {
    int e = tid * 16 + q * 4;
    *(f32x4*)(sout + (size_t)bh * 4096 + e) = *(const f32x4*)(Sb + e);
  }
}

// ---------------- apply chunk-start state: o += Z @ S0 (per chunk) ----------------
__global__ __launch_bounds__(256) void k_scanO(
    const unsigned short* __restrict__ Zg, const float* __restrict__ Scg,
    float* __restrict__ o) {
  const int blk = blockIdx.x;
  const int c = blk & (NC_ - 1), bh = blk >> 4;
  const int b = bh >> 5, h = bh & (H_ - 1);
  const int l = threadIdx.x & 63;
  const int w = threadIdx.x >> 6;
  float S[64];
  const float* Sp = Scg + (size_t)blk * 4096 + l;
#pragma unroll
  for (int k = 0; k < 64; ++k) S[k] = Sp[(size_t)k * 64];
  size_t zb = (size_t)blk * 8192;
  size_t ob = (size_t)b * ((size_t)T_ * C_) + (size_t)(c * L_) * C_ + h * 64 + l;
  for (int tt = 0; tt < 32; ++tt) {
    int t = w * 32 + tt;
    float zv = bf2f(Zg[zb + t * 64 + l]);  // lane l holds z_t[l]
    float a0_ = 0.f, a1_ = 0.f, a2_ = 0.f, a3_ = 0.f;
#pragma unroll
    for (int k = 0; k < 64; k += 4) {
      a0_ = fmaf(rlane(zv, k), S[k], a0_);
      a1_ = fmaf(rlane(zv, k + 1), S[k + 1], a1_);
      a2_ = fmaf(rlane(zv, k + 2), S[k + 2], a2_);
      a3_ = fmaf(rlane(zv, k + 3), S[k + 3], a3_);
    }
    o[ob + (size_t)t * C_] += (a0_ + a1_) + (a2_ + a3_);
  }
}

// ---------------- post-scan: GroupNorm + bonus + *g -> bf16 ----------------
__global__ __launch_bounds__(256) void k_post(
    const float* __restrict__ o, const float* __restrict__ vp, const float* __restrict__ gp,
    const float* __restrict__ dp,
    const float* __restrict__ lnw, const float* __restrict__ lnb,
    unsigned short* __restrict__ z) {
  int gw = blockIdx.x * 4 + (threadIdx.x >> 6);
  int l = threadIdx.x & 63;
  int h = gw & (H_ - 1);
  size_t bt = (size_t)(gw >> 5);
  size_t idx = bt * C_ + h * 64 + l;
  int c = h * 64 + l;
  float ov = o[idx];
  float s1 = ov;
#pragma unroll
  for (int m = 1; m < 64; m <<= 1) s1 += __shfl_xor(s1, m);
  float mu = s1 * (1.f / 64.f);
  float d = ov - mu;
  float s2 = d * d;
#pragma unroll
  for (int m = 1; m < 64; m <<= 1) s2 += __shfl_xor(s2, m);
  float var = s2 * (1.f / 64.f);
  float y = d * rsqrtf(var + 6.4e-4f);
  y = y * lnw[c] + lnb[c];
  y = fmaf(dp[bt * H_ + h], vp[idx], y);
  z[idx] = f2bf(y * gp[idx]);
}

extern "C" void kernel_launch(void* const* d_in, const int* in_sizes, int n_in,
                              void* d_out, int out_size, void* d_ws, size_t ws_size,
                              hipStream_t stream) {
  const float* x      = (const float*)d_in[0];
  const float* shift  = (const float*)d_in[1];
  const float* wkv    = (const float*)d_in[2];
  const float* vfirst = (const float*)d_in[3];
  const float* x_r    = (const float*)d_in[4];
  const float* x_w    = (const float*)d_in[5];
  const float* x_k    = (const float*)d_in[6];
  const float* x_v    = (const float*)d_in[7];
  const float* x_a    = (const float*)d_in[8];
  const float* x_g    = (const float*)d_in[9];
  const float* w0     = (const float*)d_in[10];
  const float* w1     = (const float*)d_in[11];
  const float* w2     = (const float*)d_in[12];
  const float* a0     = (const float*)d_in[13];
  const float* a1     = (const float*)d_in[14];
  const float* a2     = (const float*)d_in[15];
  const float* v0     = (const float*)d_in[16];
  const float* v1     = (const float*)d_in[17];
  const float* v2     = (const float*)d_in[18];
  const float* g1     = (const float*)d_in[19];
  const float* g2     = (const float*)d_in[20];
  const float* k_k    = (const float*)d_in[21];
  const float* k_a    = (const float*)d_in[22];
  const float* r_k    = (const float*)d_in[23];
  const float* W_r    = (const float*)d_in[24];
  const float* W_k    = (const float*)d_in[25];
  const float* W_v    = (const float*)d_in[26];
  const float* W_o    = (const float*)d_in[27];
  const float* ln_w   = (const float*)d_in[28];
  const float* ln_b   = (const float*)d_in[29];

  // ---- workspace plan: ~213 MiB (footprint identical to passing version) ----
  char* wp = (char*)d_ws;
  auto alloc = [&](size_t bytes) { char* p = wp; wp += (bytes + 255) & ~(size_t)255; return p; };
  const size_t SB = BTC_ * 2;
  const size_t SF = BTC_ * 4;

  unsigned short* w1t = (unsigned short*)alloc((size_t)C_ * 64 * 2);
  unsigned short* w2t = (unsigned short*)alloc((size_t)C_ * 64 * 2);
  unsigned short* a1t = (unsigned short*)alloc((size_t)C_ * 64 * 2);
  unsigned short* a2t = (unsigned short*)alloc((size_t)C_ * 64 * 2);
  unsigned short* v1t = (unsigned short*)alloc((size_t)C_ * 32 * 2);
  unsigned short* v2t = (unsigned short*)alloc((size_t)C_ * 32 * 2);
  unsigned short* g1t = (unsigned short*)alloc((size_t)C_ * 128 * 2);
  unsigned short* g2t = (unsigned short*)alloc((size_t)C_ * 128 * 2);
  unsigned short* hw  = (unsigned short*)alloc((size_t)BT_ * 64 * 2);
  unsigned short* ha  = (unsigned short*)alloc((size_t)BT_ * 64 * 2);
  unsigned short* hv  = (unsigned short*)alloc((size_t)BT_ * 32 * 2);
  unsigned short* hg  = (unsigned short*)alloc((size_t)BT_ * 128 * 2);
  unsigned short* Wt2 = (unsigned short*)alloc((size_t)C_ * C_ * 2 * 2); // hi|lo; later Zg (bf16)
  float* dp           = (float*)alloc((size_t)BT_ * H_ * 4);
  unsigned short* xw  = (unsigned short*)alloc(SB);      // mix-w -> wb -> Scg (f32)
  unsigned short* xa  = (unsigned short*)alloc(SB);
  unsigned short* xg  = (unsigned short*)alloc(SB);
  unsigned short* xr2 = (unsigned short*)alloc(2 * SB); // -> kbuf f32 -> Pg|Ug -> zbuf
  unsigned short* xk2 = (unsigned short*)alloc(2 * SB); // -> vbuf f32
  unsigned short* xv2 = (unsigned short*)alloc(2 * SB); // -> scan rb|kb
  float* rbuf         = (float*)alloc(SF);              // r f32 -> g f32
  unsigned short* vbb = (unsigned short*)alloc(SB);

  unsigned short* Wh = Wt2;
  unsigned short* Wl = Wt2 + (size_t)C_ * C_;
  unsigned short* xr_h = xr2, *xr_l = xr2 + BTC_;
  unsigned short* xk_h = xk2, *xk_l = xk2 + BTC_;
  unsigned short* xv_h = xv2, *xv_l = xv2 + BTC_;
  float* kbuf = (float*)xr2;
  float* vbuf = (float*)xk2;
  unsigned short* rb = xv2;
  unsigned short* kb = xv2 + BTC_;
  float* gfull = rbuf;
  unsigned short* zbuf = (unsigned short*)xr2;
  float* Pg  = (float*)xr2;
  float* Ug  = Pg + (size_t)1024 * 4096;
  unsigned short* zg = Wt2;          // bf16 z-coefficients, 16 MiB (Wt2 dead here)
  float* Scg = (float*)xw;           // chunk-start states, 16 MiB (wb dead after scanP)

  float* outp  = (float*)d_out;
  float* xlast = outp + BTC_;
  float* soutp = outp + BTC_ + (size_t)B_ * C_;
  float* obuf  = outp;

  auto tr = [&](const float* in, unsigned short* out, int R, int Cc) {
    k_tr<<<dim3(Cc / 32, R / 32), 256, 0, stream>>>(in, out, R, Cc);
  };
  auto gemm = [&](const unsigned short* X, const unsigned short* Wtp, void* out,
                  int M, int N, int K, int mode) {
    k_gemm<<<dim3((N + 127) / 128, M / 128), 256, 0, stream>>>(X, Wtp, out, M, N, K, mode);
  };
  auto gemm2 = [&](const unsigned short* Xh_, const unsigned short* Xl_, int xlo,
                   const unsigned short* Wh_, const unsigned short* Wl_, int wlo,
                   void* out, int M, int N, int K, int mode) {
    k_gemm2<<<dim3((N + 127) / 128, M / 128), 256, 0, stream>>>(Xh_, Xl_, xlo, Wh_, Wl_, wlo,
                                                                out, M, N, K, mode);
  };

  k_mix<<<(int)(BTC_ / 4 / 256), 256, 0, stream>>>(x, shift, x_r, x_w, x_k, x_v, x_a, x_g,
                                                   xr_h, xr_l, xk_h, xk_l, xv_h, xv_l,
                                                   xw, xa, xg, xlast);
  tr(w1, w1t, C_, 64);  tr(w2, w2t, 64, C_);
  tr(a1, a1t, C_, 64);  tr(a2, a2t, 64, C_);
  tr(v1, v1t, C_, 32);  tr(v2, v2t, 32, C_);
  tr(g1, g1t, C_, 128); tr(g2, g2t, 128, C_);

  // LoRA stage 1
  gemm(xw, w1t, hw, BT_, 64, C_, 2);
  gemm(xa, a1t, ha, BT_, 64, C_, 1);
  gemm2(xv_h, xv_l, 1, v1t, nullptr, 0, hv, BT_, 32, C_, 1);
  gemm(xg, g1t, hg, BT_, 128, C_, 3);

  // big projections, split precision (hh + lh + hl)
  k_trs<<<dim3(C_ / 32, C_ / 32), 256, 0, stream>>>(W_r, Wh, Wl, C_, C_);
  gemm2(xr_h, xr_l, 1, Wh, Wl, 1, rbuf, BT_, C_, C_, 0);
  k_trs<<<dim3(C_ / 32, C_ / 32), 256, 0, stream>>>(W_k, Wh, Wl, C_, C_);
  gemm2(xk_h, xk_l, 1, Wh, Wl, 1, kbuf, BT_, C_, C_, 0);
  k_trs<<<dim3(C_ / 32, C_ / 32), 256, 0, stream>>>(W_v, Wh, Wl, C_, C_);
  gemm2(xv_h, xv_l, 1, Wh, Wl, 1, vbuf, BT_, C_, C_, 0);

  // LoRA stage 2 into dead mix buffers
  gemm(hw, w2t, xw, BT_, C_, 64, 1);
  gemm(ha, a2t, xa, BT_, C_, 64, 1);
  gemm(hv, v2t, xg, BT_, C_, 32, 1);

  k_pre<<<BT_ * H_ / 4, 256, 0, stream>>>(rbuf, kbuf, vbuf, xw, xa, xg, vfirst,
                                          w0, a0, v0, k_k, k_a, r_k,
                                          rb, xw, kb, vbb, xa, xg, dp);

  gemm(hg, g2t, gfull, BT_, C_, 128, 0);

  // chunk-parallel scan: P/U/z/y in one pass, combine, then apply S0 (no replay)
  k_scanP<<<B_ * H_ * NC_, 64, 0, stream>>>(rb, xw, kb, vbb, xa, xg, Pg, Ug, zg, obuf);
  k_scanC<<<B_ * H_, 256, 0, stream>>>(Pg, Ug, wkv, Scg, soutp);
  k_scanO<<<B_ * H_ * NC_, 256, 0, stream>>>(zg, Scg, obuf);

  k_post<<<BT_ * H_ / 4, 256, 0, stream>>>(obuf, vbuf, gfull, dp, ln_w, ln_b, zbuf);

  tr(W_o, Wh, C_, C_);
  gemm(zbuf, Wh, outp, BT_, C_, C_, 0);
}